// Round 12
// baseline (3912.491 us; speedup 1.0000x reference)
//
#include <hip/hip_runtime.h>
#include <math.h>

// Problem constants: B=4096, SORB=64, H=256, NELE=32 (alpha=16), 2 GRU layers
#define BB 4096
#define SS 64
#define HH 256
#define NGR 32     // groups
#define PWG 8      // WGs per group; WG owns 32 units (2 unit-tiles x 3 gates = 6 nt)
#define RG 128     // rows per group; wave w = mtile w (16 rows)
#define NT 512

typedef __attribute__((ext_vector_type(8))) _Float16 half8;
typedef __attribute__((ext_vector_type(4))) float    f32x4;

__device__ __forceinline__ float sigmoidf_(float v){ return 1.f/(1.f+expf(-v)); }
#define MFMA16(A,B,C) __builtin_amdgcn_mfma_f32_16x16x32_f16((A),(B),(C),0,0,0)

// group sync: monotonic counter, device-scope. Every WG: fence, +1, spin to target.
__device__ __forceinline__ void gsync(unsigned int* f, unsigned int tgt){
    __syncthreads();                      // drains this WG's memory ops
    if (threadIdx.x == 0){
        __threadfence();                  // publish writes + L1 writeback/inv
        atomicAdd(f, 1u);
        long long guard = 0;
        while (__hip_atomic_load(f, __ATOMIC_ACQUIRE, __HIP_MEMORY_SCOPE_AGENT) < tgt){
            if (++guard > 100000000LL) break;   // ~bounded: avoid eternal hang
        }
        __threadfence();                  // invalidate L1 before consuming others' data
    }
    __syncthreads();
}

__global__ __launch_bounds__(NT, 1) void rnn_mp(
    const int*   __restrict__ x,      // (B,S) +/-1, pristine
    const float* __restrict__ Wih0,   // (768,2) pristine
    float* whh0m, float* wih1m, float* whh1m,   // f32 weights; later reused as HB1 (fp16 h1)
    const float* __restrict__ Wl,     // (2,256)
    const float* __restrict__ bl,     // (2,)
    _Float16* hb0,                    // d_ws: h0 exchange, 4096x256 fp16 (memset 0)
    unsigned int* flags,              // d_ws+2MB: [32][4] step flags + [128] init counter (memset 0)
    float* out)                       // (B,) = real(wf)
{
    // LDS: weight slice (144 KB) + small tables
    __shared__ _Float16 Bl[3*6*8*512];          // [mat][lf][kt][512]  147456 B
    __shared__ float    g0w[32][6];             // layer-0 input-gate weights for owned units
    __shared__ unsigned long long bitsS[RG];    // per-row step bits
    __shared__ float    wls[2*HH];
    __shared__ float    red[16][33][2];         // logits partials (rows x segs)

    const int g  = blockIdx.x & 31;    // group: members {g, g+32, ...} -> same XCD (%8 heuristic)
    const int p  = blockIdx.x >> 5;    // WG index in group, owns units [32p, 32p+32)
    const int t  = threadIdx.x;
    const int L  = t & 63;
    const int w  = t >> 6;             // wave = mtile (rows 16w..16w+16 of the group)
    const int lm = L & 15;
    const int quad = L >> 4;
    const int r0 = RG * g;             // group's global row base

    _Float16* hb0g = hb0 + (size_t)r0 * HH;
    _Float16* hb1g;                    // HB1 lives in the three weight buffers (512 B/row)
    if      (r0 < 1536) hb1g = (_Float16*)whh0m + (size_t)r0 * HH;
    else if (r0 < 3072) hb1g = (_Float16*)wih1m + (size_t)(r0 - 1536) * HH;
    else                hb1g = (_Float16*)whh1m + (size_t)(r0 - 3072) * HH;

    unsigned int* fgA = flags + g*4 + 0;
    unsigned int* fgB = flags + g*4 + 1;
    unsigned int* fgC = flags + g*4 + 2;
    unsigned int* fgD = flags + g*4 + 3;
    unsigned int* initc = flags + 128;

    // ---------------- init: pack weight slice f32 -> fp16 MFMA-B frags in LDS ----------------
    // frag(mat, lf=gate*2+lut, kt): half[lane*8+j] = W[gate*256 + 32p + lut*16 + (lane&15)][kt*32+(lane>>4)*8+j]
    for (int i = t; i < 3*6*8*64; i += NT){
        int lane = i & 63, kt = (i>>6) & 7, lf = (i>>9) % 6, mat = i / (6*8*64);
        const float* W = (mat==0) ? whh0m : (mat==1) ? wih1m : whh1m;
        int gt = lf >> 1, lut = lf & 1;
        int grow = gt*HH + 32*p + lut*16 + (lane & 15);
        int kb = kt*32 + (lane>>4)*8;
        _Float16* d = Bl + ((mat*6 + lf)*8 + kt)*512 + lane*8;
        #pragma unroll
        for (int j=0;j<8;++j) d[j] = (_Float16)W[grow*HH + kb + j];
    }
    for (int i = t; i < 192; i += NT){
        int ul = i / 6, c = i % 6;
        int gate = c >> 1, col = c & 1;
        g0w[ul][c] = Wih0[(gate*HH + 32*p + ul)*2 + col];
    }
    for (int i = t; i < 2*HH; i += NT) wls[i] = Wl[i];
    for (int i = t; i < RG; i += NT){
        unsigned long long b = 0;
        for (int s = 0; s < SS; ++s)
            b |= (unsigned long long)(x[(size_t)(r0+i)*SS + s] > 0) << s;
        bitsS[i] = b;
    }
    const float bl0 = bl[0], bl1 = bl[1];

    gsync(initc, 256);     // all WGs finished reading pristine f32 weights

    // zero this WG's HB1 slice (rows of group, its 32 units)
    {
        half8 z8 = {};
        for (int i = t; i < RG*4; i += NT){
            int lr = i >> 2, ch = i & 3;
            *((half8*)(hb1g + (size_t)lr*HH + 32*p) + ch) = z8;
        }
    }
    gsync(initc, 512);     // HB1 zeros visible everywhere

    float amp=1.f, ph=0.f, nup=0.f, ndn=0.f;   // owned by t<16 (rows 16p+t)

    for (int step = 0; step < SS; ++step){
        // ---------------- GEMM0: gates0 = h0 @ Whh0_slice^T ----------------
        f32x4 a0c[3][2] = {};   // [gate][lut]
        {
            const _Float16* ab = hb0g + (size_t)(16*w + lm)*HH + quad*8;
            half8 p0 = *(const half8*)(ab);
            half8 p1 = *(const half8*)(ab + 32);
            for (int kt = 0; kt < 8; ++kt){
                half8 ac = p0; p0 = p1;
                if (kt < 6) p1 = *(const half8*)(ab + (kt+2)*32);
                #pragma unroll
                for (int gt=0; gt<3; ++gt){
                    #pragma unroll
                    for (int lut=0; lut<2; ++lut){
                        half8 Bv = *(const half8*)(Bl + ((0*6 + gt*2+lut)*8 + kt)*512 + L*8);
                        a0c[gt][lut] = MFMA16(ac, Bv, a0c[gt][lut]);
                    }
                }
            }
        }
        gsync(fgA, PWG*(step+1));   // all WGs done reading h0

        // ---------------- elementwise 0: update owned units, all group rows ----------------
        #pragma unroll
        for (int lut=0; lut<2; ++lut){
            int ul = lut*16 + lm;
            int gu = 32*p + ul;
            #pragma unroll
            for (int reg=0; reg<4; ++reg){
                int lr = 16*w + quad*4 + reg;
                float gr=0.f, gz=0.f, gn=0.f;
                if (step > 0){
                    int c = (int)((bitsS[lr] >> (step-1)) & 1ULL);
                    gr = g0w[ul][c]; gz = g0w[ul][2+c]; gn = g0w[ul][4+c];
                }
                float r = sigmoidf_(gr + a0c[0][lut][reg]);
                float z = sigmoidf_(gz + a0c[1][lut][reg]);
                float n = tanhf(gn + r*a0c[2][lut][reg]);
                _Float16* hp = hb0g + (size_t)lr*HH + gu;
                float hold = (float)(*hp);
                *hp = (_Float16)((1.f - z)*n + z*hold);
            }
        }
        gsync(fgB, PWG*(step+1));   // h0n published

        // ---------------- GEMM1: r,z = h0n@Wih1 + h1@Whh1 ; nI,nH split ----------------
        f32x4 aR[2]={}, aZ[2]={}, aNI[2]={}, aNH[2]={};
        {
            const _Float16* a0b = hb0g + (size_t)(16*w + lm)*HH + quad*8;
            const _Float16* a1b = hb1g + (size_t)(16*w + lm)*HH + quad*8;
            half8 q00 = *(const half8*)(a0b),      q01 = *(const half8*)(a0b + 32);
            half8 q10 = *(const half8*)(a1b),      q11 = *(const half8*)(a1b + 32);
            for (int kt = 0; kt < 8; ++kt){
                half8 A0 = q00; q00 = q01;
                half8 A1 = q10; q10 = q11;
                if (kt < 6){
                    q01 = *(const half8*)(a0b + (kt+2)*32);
                    q11 = *(const half8*)(a1b + (kt+2)*32);
                }
                #pragma unroll
                for (int lut=0; lut<2; ++lut){
                    half8 B1r = *(const half8*)(Bl + ((1*6 + 0+lut)*8 + kt)*512 + L*8);
                    half8 B2r = *(const half8*)(Bl + ((2*6 + 0+lut)*8 + kt)*512 + L*8);
                    half8 B1z = *(const half8*)(Bl + ((1*6 + 2+lut)*8 + kt)*512 + L*8);
                    half8 B2z = *(const half8*)(Bl + ((2*6 + 2+lut)*8 + kt)*512 + L*8);
                    half8 B1n = *(const half8*)(Bl + ((1*6 + 4+lut)*8 + kt)*512 + L*8);
                    half8 B2n = *(const half8*)(Bl + ((2*6 + 4+lut)*8 + kt)*512 + L*8);
                    aR[lut]  = MFMA16(A0, B1r, aR[lut]);
                    aR[lut]  = MFMA16(A1, B2r, aR[lut]);
                    aZ[lut]  = MFMA16(A0, B1z, aZ[lut]);
                    aZ[lut]  = MFMA16(A1, B2z, aZ[lut]);
                    aNI[lut] = MFMA16(A0, B1n, aNI[lut]);
                    aNH[lut] = MFMA16(A1, B2n, aNH[lut]);
                }
            }
        }
        gsync(fgC, PWG*(step+1));   // all WGs done reading h1 (and h0n)

        // ---------------- elementwise 1 ----------------
        #pragma unroll
        for (int lut=0; lut<2; ++lut){
            int gu = 32*p + lut*16 + lm;
            #pragma unroll
            for (int reg=0; reg<4; ++reg){
                int lr = 16*w + quad*4 + reg;
                float r = sigmoidf_(aR[lut][reg]);
                float z = sigmoidf_(aZ[lut][reg]);
                float n = tanhf(aNI[lut][reg] + r*aNH[lut][reg]);
                _Float16* hp = hb1g + (size_t)lr*HH + gu;
                float hold = (float)(*hp);
                *hp = (_Float16)((1.f - z)*n + z*hold);
            }
        }
        gsync(fgD, PWG*(step+1));   // h1n published

        // ---------------- logits + sampling for this WG's 16 rows ----------------
        {
            int rr = t >> 5, s2 = t & 31;
            int lr = 16*p + rr;
            half8 hv = *(const half8*)(hb1g + (size_t)lr*HH + s2*8);
            float s0=0.f, s1=0.f;
            #pragma unroll
            for (int j=0;j<8;++j){
                float h = (float)hv[j];
                s0 += h * wls[s2*8+j];
                s1 += h * wls[HH + s2*8+j];
            }
            red[rr][s2][0] = s0; red[rr][s2][1] = s1;
        }
        __syncthreads();
        if (t < 16){
            float l0 = bl0, l1 = bl1;
            #pragma unroll
            for (int s2=0; s2<32; ++s2){ l0 += red[t][s2][0]; l1 += red[t][s2][1]; }

            bool  ev  = (step & 1) == 0;
            float low = -16.f + (float)(step >> 1);
            float cnt = ev ? nup : ndn;
            float mocc = (16.f > cnt) ? 1.f : 0.f;
            float mun  = (low  < cnt) ? 1.f : 0.f;

            float mx = fmaxf(l0, l1);
            float e0 = expf(l0-mx), e1 = expf(l1-mx);
            float inv = 1.f/(e0+e1);
            float a0 = sqrtf(e0*inv)*mun;
            float a1 = sqrtf(e1*inv)*mocc;
            float nrm = sqrtf(a0*a0 + a1*a1);
            float den = fmaxf(nrm, 1e-12f);
            a0 /= den; a1 /= den;

            const float PI_F = 3.14159265358979323846f;
            float p0 = PI_F*l0/(1.f+fabsf(l0));
            float p1 = PI_F*l1/(1.f+fabsf(l1));

            int bit = (int)((bitsS[16*p + t] >> step) & 1ULL);
            amp *= bit ? a1 : a0;
            ph  += bit ? p1 : p0;
            if (ev) nup += (float)bit; else ndn += (float)bit;
        }
        // red reuse guarded by the 4 gsyncs of the next step
    }

    if (t < 16) out[r0 + 16*p + t] = amp * cosf(ph);
}

extern "C" void kernel_launch(void* const* d_in, const int* in_sizes, int n_in,
                              void* d_out, int out_size, void* d_ws, size_t ws_size,
                              hipStream_t stream) {
    (void)in_sizes; (void)n_in; (void)out_size; (void)ws_size;
    const int*   x    = (const int*)d_in[0];
    const float* Wih0 = (const float*)d_in[1];
    float*       Whh0 = (float*)d_in[2];   // consumed at init, then reused as HB1 rows [0,1536)
    float*       Wih1 = (float*)d_in[3];   // ... HB1 rows [1536,3072)
    float*       Whh1 = (float*)d_in[4];   // ... HB1 rows [3072,4096)
    const float* Wl   = (const float*)d_in[5];
    const float* bl   = (const float*)d_in[6];
    float* out = (float*)d_out;

    _Float16*     hb0   = (_Float16*)d_ws;                          // 2 MB
    unsigned int* flags = (unsigned int*)((char*)d_ws + (2u<<20));  // 516 B used

    // zero h0 exchange buffer + flags (graph-capture-safe async memset)
    hipMemsetAsync(d_ws, 0, (2u<<20) + 4096, stream);

    rnn_mp<<<NGR*PWG, NT, 0, stream>>>(x, Wih0, Whh0, Wih1, Whh1, Wl, bl, hb0, flags, out);
}